// Round 1
// baseline (132.740 us; speedup 1.0000x reference)
//
#include <hip/hip_runtime.h>
#include <hip/hip_bf16.h>

// Problem constants
#define AA 4
#define NN 384
#define DD 256
#define HH 8
#define CC 32

// ---------------------------------------------------------------------------
// Kernel 1: projection GEMM  Y = X * W^T + b
//   X: (1536, 256) row-major (a*384+n, k)
//   W: (256, 256) row-major (d, k)
//   out stored permuted: out[((a*8+h)*384 + n)*32 + c], d = h*32+c
// grid (24, 4), block 256. 64x64 tile, K-chunks of 16.
// ---------------------------------------------------------------------------
__global__ __launch_bounds__(256) void proj_kernel(
    const float* __restrict__ X, const float* __restrict__ W,
    const float* __restrict__ bias, float* __restrict__ out)
{
    __shared__ float Xs[64][17];
    __shared__ float Ws[64][17];
    const int tid = threadIdx.x;
    const int row0 = blockIdx.x * 64;
    const int col0 = blockIdx.y * 64;
    const int tx = tid & 15;
    const int ty = tid >> 4;

    float acc[4][4];
    #pragma unroll
    for (int i = 0; i < 4; ++i)
        #pragma unroll
        for (int j = 0; j < 4; ++j) acc[i][j] = 0.f;

    for (int kt = 0; kt < 256; kt += 16) {
        const int r  = tid >> 2;        // 0..63
        const int k4 = (tid & 3) * 4;   // 0,4,8,12
        float4 xv = *(const float4*)&X[(row0 + r) * 256 + kt + k4];
        Xs[r][k4 + 0] = xv.x; Xs[r][k4 + 1] = xv.y;
        Xs[r][k4 + 2] = xv.z; Xs[r][k4 + 3] = xv.w;
        float4 wv = *(const float4*)&W[(col0 + r) * 256 + kt + k4];
        Ws[r][k4 + 0] = wv.x; Ws[r][k4 + 1] = wv.y;
        Ws[r][k4 + 2] = wv.z; Ws[r][k4 + 3] = wv.w;
        __syncthreads();
        #pragma unroll
        for (int kk = 0; kk < 16; ++kk) {
            float xr[4], wc[4];
            #pragma unroll
            for (int i = 0; i < 4; ++i) xr[i] = Xs[ty + 16 * i][kk];
            #pragma unroll
            for (int j = 0; j < 4; ++j) wc[j] = Ws[tx + 16 * j][kk];
            #pragma unroll
            for (int i = 0; i < 4; ++i)
                #pragma unroll
                for (int j = 0; j < 4; ++j) acc[i][j] += xr[i] * wc[j];
        }
        __syncthreads();
    }

    #pragma unroll
    for (int i = 0; i < 4; ++i) {
        const int row = row0 + ty + 16 * i;
        const int a = row / 384;
        const int n = row - a * 384;
        #pragma unroll
        for (int j = 0; j < 4; ++j) {
            const int d = col0 + tx + 16 * j;
            const int h = d >> 5;
            const int c = d & 31;
            out[((a * 8 + h) * 384 + n) * 32 + c] = acc[i][j] + bias[d];
        }
    }
}

// ---------------------------------------------------------------------------
// Kernel 2: per (a,e,h, n-half) attention with online softmax.
//   Also accumulates raw score sum (pre-softmax, scaled) -> msum partials.
//   S(a,e)[h][n][c] written unweighted to Sout.
// grid 256 = ((a*4+e)*8+h)*2 + t, block 192 (thread = one row n).
// ---------------------------------------------------------------------------
__global__ __launch_bounds__(192) void attn_kernel(
    const float* __restrict__ qb, const float* __restrict__ kb,
    const float* __restrict__ vb, float* __restrict__ Sout,
    float* __restrict__ msum_part)
{
    __shared__ float ks[384 * 32];
    __shared__ float vs[384 * 32];
    __shared__ float red[192];

    const int bid = blockIdx.x;
    const int t = bid & 1;
    const int h = (bid >> 1) & 7;
    const int e = (bid >> 4) & 3;
    const int a = bid >> 6;
    const int tid = threadIdx.x;

    const float* kp = kb + (e * 8 + h) * 384 * 32;
    const float* vp = vb + (e * 8 + h) * 384 * 32;

    // stage K and V into LDS (3072 float4 each; 16 per thread)
    #pragma unroll
    for (int j = 0; j < 16; ++j) {
        const int i4 = tid + 192 * j;
        ((float4*)ks)[i4] = ((const float4*)kp)[i4];
        ((float4*)vs)[i4] = ((const float4*)vp)[i4];
    }
    __syncthreads();

    const int n = t * 192 + tid;
    const float* qp = qb + ((a * 8 + h) * 384 + n) * 32;
    float qv[32];
    #pragma unroll
    for (int c4 = 0; c4 < 8; ++c4) {
        float4 q4 = ((const float4*)qp)[c4];
        qv[4 * c4 + 0] = q4.x; qv[4 * c4 + 1] = q4.y;
        qv[4 * c4 + 2] = q4.z; qv[4 * c4 + 3] = q4.w;
    }

    float acc[32];
    #pragma unroll
    for (int c = 0; c < 32; ++c) acc[c] = 0.f;
    float mx = -INFINITY, l = 0.f, rawsum = 0.f;
    const float sc = 0.17677669529663687f; // 1/sqrt(32)

    for (int m0 = 0; m0 < 384; m0 += 8) {
        float s[8];
        #pragma unroll
        for (int j = 0; j < 8; ++j) {
            const float4* kr = (const float4*)&ks[(m0 + j) * 32];
            float t0 = 0.f, t1 = 0.f, t2 = 0.f, t3 = 0.f;
            #pragma unroll
            for (int c4 = 0; c4 < 8; ++c4) {
                float4 kv = kr[c4];
                t0 += qv[4 * c4 + 0] * kv.x;
                t1 += qv[4 * c4 + 1] * kv.y;
                t2 += qv[4 * c4 + 2] * kv.z;
                t3 += qv[4 * c4 + 3] * kv.w;
            }
            s[j] = (t0 + t1 + t2 + t3) * sc;
        }
        float cm = s[0];
        #pragma unroll
        for (int j = 1; j < 8; ++j) cm = fmaxf(cm, s[j]);
        #pragma unroll
        for (int j = 0; j < 8; ++j) rawsum += s[j];

        const float nm = fmaxf(mx, cm);
        const float scale = __expf(mx - nm); // first iter: exp(-inf)=0
        mx = nm;
        l *= scale;
        #pragma unroll
        for (int c = 0; c < 32; ++c) acc[c] *= scale;

        float p[8];
        #pragma unroll
        for (int j = 0; j < 8; ++j) { p[j] = __expf(s[j] - nm); l += p[j]; }

        #pragma unroll
        for (int j = 0; j < 8; ++j) {
            const float pj = p[j];
            const float4* vr = (const float4*)&vs[(m0 + j) * 32];
            #pragma unroll
            for (int c4 = 0; c4 < 8; ++c4) {
                float4 vv = vr[c4];
                acc[4 * c4 + 0] += pj * vv.x;
                acc[4 * c4 + 1] += pj * vv.y;
                acc[4 * c4 + 2] += pj * vv.z;
                acc[4 * c4 + 3] += pj * vv.w;
            }
        }
    }

    const float inv = 1.f / l;
    float* so = Sout + (((a * 4 + e) * 8 + h) * 384 + n) * 32;
    #pragma unroll
    for (int c4 = 0; c4 < 8; ++c4) {
        float4 o;
        o.x = acc[4 * c4 + 0] * inv; o.y = acc[4 * c4 + 1] * inv;
        o.z = acc[4 * c4 + 2] * inv; o.w = acc[4 * c4 + 3] * inv;
        ((float4*)so)[c4] = o;
    }

    // block reduction of raw score sums (deterministic, no atomics)
    red[tid] = rawsum;
    __syncthreads();
    for (int off = 96; off >= 3; off >>= 1) {
        if (tid < off) red[tid] += red[tid + off];
        __syncthreads();
    }
    if (tid == 0)
        msum_part[(a * 4 + e) * 16 + h * 2 + t] = red[0] + red[1] + red[2];
}

// ---------------------------------------------------------------------------
// Kernel 3: reduce partials -> 16 means -> pooled[12] -> attn_r -> w[16]
// single block, 256 threads
// ---------------------------------------------------------------------------
__global__ __launch_bounds__(256) void stats_kernel(
    const float* __restrict__ msum_part, float* __restrict__ wout)
{
    __shared__ float part[256];
    __shared__ float cell[16];
    const int tid = threadIdx.x;
    part[tid] = msum_part[tid];
    __syncthreads();
    if (tid < 16) {
        float s = 0.f;
        #pragma unroll
        for (int j = 0; j < 16; ++j) s += part[tid * 16 + j];
        cell[tid] = s;
    }
    __syncthreads();
    if (tid == 0) {
        const int TR[12][4] = {
            {0,1,2,3},{0,2,3,1},{0,3,1,2},{1,2,0,3},{1,0,3,2},{1,3,2,0},
            {2,3,0,1},{2,0,1,3},{2,1,3,0},{3,1,0,2},{3,0,2,1},{3,2,1,0}};
        const float denom = 4.0f * 8.0f * 384.0f * 384.0f;
        float pos[12];
        float psum = 0.f;
        for (int r = 0; r < 12; ++r) {
            float s = 0.f;
            for (int a = 0; a < 4; ++a) s += cell[a * 4 + TR[r][a]];
            const float pooled = s / denom;
            pos[r] = pooled * pooled;
            psum += pos[r];
        }
        float w[16];
        for (int i = 0; i < 16; ++i) w[i] = 0.f;
        const float ip = 1.f / psum;
        for (int r = 0; r < 12; ++r)
            for (int a = 0; a < 4; ++a) w[a * 4 + TR[r][a]] += pos[r] * ip;
        for (int i = 0; i < 16; ++i) wout[i] = w[i];
    }
}

// ---------------------------------------------------------------------------
// Kernel 4: out[a,n,h*32+c] = sum_e w[a,e] * S[(a,e),h,n,c]
// grid 1536, block 256
// ---------------------------------------------------------------------------
__global__ __launch_bounds__(256) void combine_kernel(
    const float* __restrict__ S, const float* __restrict__ w,
    float* __restrict__ out)
{
    const int idx = blockIdx.x * 256 + threadIdx.x; // < 393216
    const int a = idx / 98304;
    const int rem = idx - a * 98304;
    const int n = rem >> 8;
    const int d = rem & 255;
    const int h = d >> 5;
    const int c = d & 31;
    float r = 0.f;
    #pragma unroll
    for (int e = 0; e < 4; ++e)
        r += w[a * 4 + e] * S[(((a * 4 + e) * 8 + h) * 384 + n) * 32 + c];
    out[idx] = r;
}

// ---------------------------------------------------------------------------
extern "C" void kernel_launch(void* const* d_in, const int* in_sizes, int n_in,
                              void* d_out, int out_size, void* d_ws, size_t ws_size,
                              hipStream_t stream)
{
    const float* in_q = (const float*)d_in[0];
    const float* in_k = (const float*)d_in[1];
    const float* in_v = (const float*)d_in[2];
    const float* Wq   = (const float*)d_in[3];
    const float* bq   = (const float*)d_in[4];
    const float* Wk   = (const float*)d_in[5];
    const float* bk   = (const float*)d_in[6];
    const float* Wv   = (const float*)d_in[7];
    const float* bv   = (const float*)d_in[8];

    float* ws  = (float*)d_ws;
    float* qb  = ws;                  // 393216
    float* kb  = qb + 393216;         // 393216
    float* vb  = kb + 393216;         // 393216
    float* Sb  = vb + 393216;         // 1572864
    float* ms  = Sb + 1572864;        // 256
    float* wb  = ms + 256;            // 16
    float* outp = (float*)d_out;

    dim3 pgrid(24, 4);
    proj_kernel<<<pgrid, 256, 0, stream>>>(in_q, Wq, bq, qb);
    proj_kernel<<<pgrid, 256, 0, stream>>>(in_k, Wk, bk, kb);
    proj_kernel<<<pgrid, 256, 0, stream>>>(in_v, Wv, bv, vb);
    attn_kernel<<<256, 192, 0, stream>>>(qb, kb, vb, Sb, ms);
    stats_kernel<<<1, 256, 0, stream>>>(ms, wb);
    combine_kernel<<<1536, 256, 0, stream>>>(Sb, wb, outp);
}